// Round 1
// baseline (2775.992 us; speedup 1.0000x reference)
//
#include <hip/hip_runtime.h>
#include <hip/hip_bf16.h>
#include <float.h>

// PatchCore NN-distance: nn_dists[q] = min_m ||query_q - memory_m||_2, plus max over q.
// Rows are L2-normalized => d2 = 2 - 2*(q.m)  (|q|^2,|m|^2 = 1 +- ~1e-5, << 2.7e-2 threshold).
// Core = bf16 MFMA GEMM (Q x M, K=1536) with min-reduce epilogue (no S matrix materialized).

#define QN 4096
#define MN 100000
#define DN 1536
#define BK 32
#define NKIT (DN / BK)        // 48
#define LDSS 40               // LDS row stride in shorts: 32 + 8 pad -> 80B rows, 16B aligned

typedef __attribute__((ext_vector_type(8))) short short8;   // bf16x8 MFMA operand (4 VGPRs)
typedef __attribute__((ext_vector_type(4))) short short4v;  // 8B LDS store
typedef __attribute__((ext_vector_type(4))) float float4v;  // MFMA accumulator

__device__ __forceinline__ short f2bf(float f) {            // fp32 -> bf16 RNE
    unsigned u = __float_as_uint(f);
    u += 0x7FFFu + ((u >> 16) & 1u);
    return (short)(u >> 16);
}
// monotone float<->uint map so atomicMin(uint) == min(float)
__device__ __forceinline__ unsigned encf(float f) {
    unsigned u = __float_as_uint(f);
    return (u & 0x80000000u) ? ~u : (u | 0x80000000u);
}
__device__ __forceinline__ float decf(unsigned e) {
    unsigned u = (e & 0x80000000u) ? (e & 0x7FFFFFFFu) : ~e;
    return __uint_as_float(u);
}

__global__ void init_min(unsigned* __restrict__ dminEnc) {
    int i = blockIdx.x * blockDim.x + threadIdx.x;
    if (i < QN) dminEnc[i] = 0xFF7FFFFFu;  // encf(FLT_MAX)
}

__global__ __launch_bounds__(256, 2)
void nn_gemm(const float* __restrict__ query, const float* __restrict__ memory,
             unsigned* __restrict__ dminEnc)
{
    __shared__ __align__(16) short As[128 * LDSS];
    __shared__ __align__(16) short Bs[128 * LDSS];
    __shared__ unsigned qmin[128];

    const int tid  = threadIdx.x;
    const int lane = tid & 63;
    const int wave = tid >> 6;
    const int wrow = wave >> 1;   // 0..1 : 64-row strip of queries
    const int wcol = wave & 1;    // 0..1 : 64-col strip of memory rows
    const int quad = lane >> 4;
    const int l16  = lane & 15;

    const int qb = blockIdx.x * 128;   // query base (always in range, 4096 % 128 == 0)
    const int mb = blockIdx.y * 128;   // memory base (last tile partially OOB)

    if (tid < 128) qmin[tid] = 0xFFFFFFFFu;

    // staging map: idx = s*256 + tid ; row = idx>>3 ; c4 = idx&7  (8 float4 per 32-col row)
    int rowS[4], c4S[4];
    const float* aPtr[4];
    const float* bPtr[4];
    bool bValid[4];
#pragma unroll
    for (int s = 0; s < 4; ++s) {
        int idx = s * 256 + tid;
        int row = idx >> 3, c4 = idx & 7;
        rowS[s] = row; c4S[s] = c4;
        aPtr[s] = query + (size_t)(qb + row) * DN + c4 * 4;
        int gr = mb + row;
        bValid[s] = (gr < MN);
        bPtr[s] = memory + (size_t)(bValid[s] ? gr : 0) * DN + c4 * 4;
    }

    float4 aReg[4], bReg[4];
#pragma unroll
    for (int s = 0; s < 4; ++s) {
        aReg[s] = *(const float4*)(aPtr[s]);
        bReg[s] = bValid[s] ? *(const float4*)(bPtr[s]) : make_float4(0.f, 0.f, 0.f, 0.f);
    }

    float4v acc[4][4];
#pragma unroll
    for (int mi = 0; mi < 4; ++mi)
#pragma unroll
        for (int ni = 0; ni < 4; ++ni)
            acc[mi][ni] = (float4v){0.f, 0.f, 0.f, 0.f};

    for (int kk = 0; kk < NKIT; ++kk) {
        // write staged regs -> LDS as bf16
#pragma unroll
        for (int s = 0; s < 4; ++s) {
            short4v pa = { f2bf(aReg[s].x), f2bf(aReg[s].y), f2bf(aReg[s].z), f2bf(aReg[s].w) };
            short4v pb = { f2bf(bReg[s].x), f2bf(bReg[s].y), f2bf(bReg[s].z), f2bf(bReg[s].w) };
            *(short4v*)&As[rowS[s] * LDSS + c4S[s] * 4] = pa;
            *(short4v*)&Bs[rowS[s] * LDSS + c4S[s] * 4] = pb;
        }
        __syncthreads();

        // prefetch next K slice (overlaps with MFMA below)
        if (kk + 1 < NKIT) {
            const int ko = (kk + 1) * BK;
#pragma unroll
            for (int s = 0; s < 4; ++s) {
                aReg[s] = *(const float4*)(aPtr[s] + ko);
                bReg[s] = bValid[s] ? *(const float4*)(bPtr[s] + ko)
                                    : make_float4(0.f, 0.f, 0.f, 0.f);
            }
        }

        // fragments: lane holds X[row = l16][k = quad*8 + 0..7]
        short8 af[4], bf[4];
#pragma unroll
        for (int mi = 0; mi < 4; ++mi)
            af[mi] = *(const short8*)&As[(wrow * 64 + mi * 16 + l16) * LDSS + quad * 8];
#pragma unroll
        for (int ni = 0; ni < 4; ++ni)
            bf[ni] = *(const short8*)&Bs[(wcol * 64 + ni * 16 + l16) * LDSS + quad * 8];

#pragma unroll
        for (int mi = 0; mi < 4; ++mi)
#pragma unroll
            for (int ni = 0; ni < 4; ++ni)
                acc[mi][ni] = __builtin_amdgcn_mfma_f32_16x16x32_bf16(
                    af[mi], bf[ni], acc[mi][ni], 0, 0, 0);
        __syncthreads();
    }

    // epilogue: d2 = 2 - 2*s ; min over this block's 128 memory cols per query row.
    // C/D layout (16x16): col = lane&15, row = quad*4 + reg.
#pragma unroll
    for (int mi = 0; mi < 4; ++mi) {
#pragma unroll
        for (int r = 0; r < 4; ++r) {
            float v = FLT_MAX;
#pragma unroll
            for (int ni = 0; ni < 4; ++ni) {
                int gcol = mb + wcol * 64 + ni * 16 + l16;
                float d2 = fmaf(-2.0f, acc[mi][ni][r], 2.0f);
                v = fminf(v, (gcol < MN) ? d2 : FLT_MAX);
            }
            // min across the 16 lanes of this quad -> min over the wave's 64 cols
            v = fminf(v, __shfl_xor(v, 1));
            v = fminf(v, __shfl_xor(v, 2));
            v = fminf(v, __shfl_xor(v, 4));
            v = fminf(v, __shfl_xor(v, 8));
            if (l16 == 0) {
                int rloc = wrow * 64 + mi * 16 + quad * 4 + r;
                atomicMin(&qmin[rloc], encf(v));
            }
        }
    }
    __syncthreads();
    if (tid < 128) atomicMin(&dminEnc[qb + tid], qmin[tid]);
}

__global__ void finalize(const unsigned* __restrict__ dminEnc, float* __restrict__ out) {
    __shared__ float red[256];
    const int tid = threadIdx.x;
    float mx = 0.f;
    for (int i = tid; i < QN; i += 256) {
        float d2 = decf(dminEnc[i]);
        float d = sqrtf(fmaxf(d2, 0.f));
        out[i] = d;
        mx = fmaxf(mx, d);
    }
    red[tid] = mx;
    __syncthreads();
    for (int s = 128; s > 0; s >>= 1) {
        if (tid < s) red[tid] = fmaxf(red[tid], red[tid + s]);
        __syncthreads();
    }
    if (tid == 0) out[QN] = red[0];
}

extern "C" void kernel_launch(void* const* d_in, const int* in_sizes, int n_in,
                              void* d_out, int out_size, void* d_ws, size_t ws_size,
                              hipStream_t stream)
{
    const float* query  = (const float*)d_in[0];
    const float* memory = (const float*)d_in[1];
    float* out = (float*)d_out;
    unsigned* dminEnc = (unsigned*)d_ws;   // QN uints

    hipLaunchKernelGGL(init_min, dim3((QN + 255) / 256), dim3(256), 0, stream, dminEnc);
    hipLaunchKernelGGL(nn_gemm, dim3(QN / 128, (MN + 127) / 128), dim3(256), 0, stream,
                       query, memory, dminEnc);
    hipLaunchKernelGGL(finalize, dim3(1), dim3(256), 0, stream, dminEnc, out);
}

// Round 2
// 2245.627 us; speedup vs baseline: 1.2362x; 1.2362x over previous
//
#include <hip/hip_runtime.h>
#include <hip/hip_bf16.h>
#include <float.h>

// PatchCore NN-distance: nn_dists[q] = min_m ||query_q - memory_m||, plus max over q.
// Rows are L2-normalized => d2 = 2 - 2*(q.m). Core = bf16 MFMA GEMM with min epilogue.
// R2: pre-convert inputs to bf16 in d_ws, m97-style global_load_lds(16B) staging.

#define QN 4096
#define MN 100000
#define MP 100096             // MN padded to multiple of 128 (pad rows zeroed)
#define DN 1536
#define BK 32
#define NKIT (DN / BK)        // 48

typedef __attribute__((ext_vector_type(8))) short short8;   // bf16x8 MFMA operand
typedef __attribute__((ext_vector_type(4))) float float4v;  // MFMA accumulator
typedef __attribute__((ext_vector_type(4))) short short4v;
typedef __attribute__((address_space(1))) const unsigned g_u32;
typedef __attribute__((address_space(3))) unsigned l_u32;

__device__ __forceinline__ short f2bf(float f) {            // fp32 -> bf16 RNE
    unsigned u = __float_as_uint(f);
    u += 0x7FFFu + ((u >> 16) & 1u);
    return (short)(u >> 16);
}
__device__ __forceinline__ unsigned encf(float f) {         // monotone float->uint
    unsigned u = __float_as_uint(f);
    return (u & 0x80000000u) ? ~u : (u | 0x80000000u);
}
__device__ __forceinline__ float decf(unsigned e) {
    unsigned u = (e & 0x80000000u) ? (e & 0x7FFFFFFFu) : ~e;
    return __uint_as_float(u);
}
__device__ __forceinline__ void gload_lds16(const void* g, void* l) {
    __builtin_amdgcn_global_load_lds((g_u32*)g, (l_u32*)l, 16, 0, 0);
}

__global__ void init_min(unsigned* __restrict__ dminEnc) {
    int i = blockIdx.x * blockDim.x + threadIdx.x;
    if (i < QN) dminEnc[i] = 0xFF7FFFFFu;  // encf(FLT_MAX)
}

// fp32 -> bf16, zero-fill [n_valid, n_total)
__global__ void cvt_bf16(const float* __restrict__ src, short* __restrict__ dst,
                         long n_valid, long n_total) {
    long i = ((long)blockIdx.x * blockDim.x + threadIdx.x) * 4;
    if (i >= n_total) return;
    if (i + 4 <= n_valid) {
        float4 v = *(const float4*)(src + i);
        short4v o = { f2bf(v.x), f2bf(v.y), f2bf(v.z), f2bf(v.w) };
        *(short4v*)(dst + i) = o;
    } else {
        for (int j = 0; j < 4; ++j)
            if (i + j < n_total) dst[i + j] = (i + j < n_valid) ? f2bf(src[i + j]) : 0;
    }
}

// ---------------- fast path: bf16 GEMM, global_load_lds staging -----------------
__global__ __launch_bounds__(256)
void nn_gemm_bf16(const short* __restrict__ qB, const short* __restrict__ mB,
                  unsigned* __restrict__ dminEnc)
{
    __shared__ __align__(16) short As[128 * BK];   // 8 KB, unpadded 64B rows
    __shared__ __align__(16) short Bs[128 * BK];   // 8 KB
    __shared__ unsigned qmin[128];

    const int tid  = threadIdx.x;
    const int lane = tid & 63;
    const int wave = tid >> 6;
    const int wrow = wave >> 1;
    const int wcol = wave & 1;
    const int quad = lane >> 4;
    const int l16  = lane & 15;

    const int qb = blockIdx.x * 128;
    const int mb = blockIdx.y * 128;

    if (tid < 128) qmin[tid] = 0xFFFFFFFFu;

    // staging: wave w, call c in {0,1}: rows w*32 + c*16 + (lane>>2), byte col (lane&3)*16
    // HW writes LDS at (wave-uniform base) + lane*16 -> exactly row-major unpadded.
    const int srow = wave * 32 + (lane >> 2);
    const int scol = (lane & 3) * 8;               // shorts
    const short* gA0 = qB + (size_t)(qb + srow) * DN + scol;
    const short* gA1 = gA0 + (size_t)16 * DN;
    const short* gB0 = mB + (size_t)(mb + srow) * DN + scol;
    const short* gB1 = gB0 + (size_t)16 * DN;
    short* lA0 = As + (wave * 32) * BK;
    short* lA1 = As + (wave * 32 + 16) * BK;
    short* lB0 = Bs + (wave * 32) * BK;
    short* lB1 = Bs + (wave * 32 + 16) * BK;

    float4v acc[4][4];
#pragma unroll
    for (int mi = 0; mi < 4; ++mi)
#pragma unroll
        for (int ni = 0; ni < 4; ++ni)
            acc[mi][ni] = (float4v){0.f, 0.f, 0.f, 0.f};

    for (int kk = 0; kk < NKIT; ++kk) {
        const size_t ko = (size_t)kk * BK;         // shorts, 64B per step
        gload_lds16(gA0 + ko, lA0);
        gload_lds16(gA1 + ko, lA1);
        gload_lds16(gB0 + ko, lB0);
        gload_lds16(gB1 + ko, lB1);
        __syncthreads();                            // drains vmcnt -> LDS valid

        short8 af[4], bf[4];
#pragma unroll
        for (int mi = 0; mi < 4; ++mi)
            af[mi] = *(const short8*)&As[(wrow * 64 + mi * 16 + l16) * BK + quad * 8];
#pragma unroll
        for (int ni = 0; ni < 4; ++ni)
            bf[ni] = *(const short8*)&Bs[(wcol * 64 + ni * 16 + l16) * BK + quad * 8];

#pragma unroll
        for (int mi = 0; mi < 4; ++mi)
#pragma unroll
            for (int ni = 0; ni < 4; ++ni)
                acc[mi][ni] = __builtin_amdgcn_mfma_f32_16x16x32_bf16(
                    af[mi], bf[ni], acc[mi][ni], 0, 0, 0);
        __syncthreads();                            // protect LDS before next stage
    }

    // epilogue: d2 = 2 - 2*s ; min over this block's 128 cols per query row.
    // C/D 16x16 layout: col = lane&15, row = quad*4 + reg.
#pragma unroll
    for (int mi = 0; mi < 4; ++mi) {
#pragma unroll
        for (int r = 0; r < 4; ++r) {
            float v = FLT_MAX;
#pragma unroll
            for (int ni = 0; ni < 4; ++ni) {
                int gcol = mb + wcol * 64 + ni * 16 + l16;
                float d2 = fmaf(-2.0f, acc[mi][ni][r], 2.0f);
                v = fminf(v, (gcol < MN) ? d2 : FLT_MAX);
            }
            v = fminf(v, __shfl_xor(v, 1));
            v = fminf(v, __shfl_xor(v, 2));
            v = fminf(v, __shfl_xor(v, 4));
            v = fminf(v, __shfl_xor(v, 8));
            if (l16 == 0) {
                int rloc = wrow * 64 + mi * 16 + quad * 4 + r;
                atomicMin(&qmin[rloc], encf(v));
            }
        }
    }
    __syncthreads();
    if (tid < 128) atomicMin(&dminEnc[qb + tid], qmin[tid]);
}

// ---------------- fallback path (round-1 kernel, fp32 inputs) -----------------
#define LDSS 40
__global__ __launch_bounds__(256, 2)
void nn_gemm_f32(const float* __restrict__ query, const float* __restrict__ memory,
                 unsigned* __restrict__ dminEnc)
{
    __shared__ __align__(16) short As[128 * LDSS];
    __shared__ __align__(16) short Bs[128 * LDSS];
    __shared__ unsigned qmin[128];

    const int tid = threadIdx.x, lane = tid & 63, wave = tid >> 6;
    const int wrow = wave >> 1, wcol = wave & 1, quad = lane >> 4, l16 = lane & 15;
    const int qb = blockIdx.x * 128, mb = blockIdx.y * 128;
    if (tid < 128) qmin[tid] = 0xFFFFFFFFu;

    int rowS[4], c4S[4];
    const float *aPtr[4], *bPtr[4];
    bool bValid[4];
#pragma unroll
    for (int s = 0; s < 4; ++s) {
        int idx = s * 256 + tid, row = idx >> 3, c4 = idx & 7;
        rowS[s] = row; c4S[s] = c4;
        aPtr[s] = query + (size_t)(qb + row) * DN + c4 * 4;
        int gr = mb + row;
        bValid[s] = (gr < MN);
        bPtr[s] = memory + (size_t)(bValid[s] ? gr : 0) * DN + c4 * 4;
    }
    float4 aReg[4], bReg[4];
#pragma unroll
    for (int s = 0; s < 4; ++s) {
        aReg[s] = *(const float4*)(aPtr[s]);
        bReg[s] = bValid[s] ? *(const float4*)(bPtr[s]) : make_float4(0.f, 0.f, 0.f, 0.f);
    }
    float4v acc[4][4];
#pragma unroll
    for (int mi = 0; mi < 4; ++mi)
#pragma unroll
        for (int ni = 0; ni < 4; ++ni) acc[mi][ni] = (float4v){0.f, 0.f, 0.f, 0.f};

    for (int kk = 0; kk < NKIT; ++kk) {
#pragma unroll
        for (int s = 0; s < 4; ++s) {
            short4v pa = { f2bf(aReg[s].x), f2bf(aReg[s].y), f2bf(aReg[s].z), f2bf(aReg[s].w) };
            short4v pb = { f2bf(bReg[s].x), f2bf(bReg[s].y), f2bf(bReg[s].z), f2bf(bReg[s].w) };
            *(short4v*)&As[rowS[s] * LDSS + c4S[s] * 4] = pa;
            *(short4v*)&Bs[rowS[s] * LDSS + c4S[s] * 4] = pb;
        }
        __syncthreads();
        if (kk + 1 < NKIT) {
            const int ko = (kk + 1) * BK;
#pragma unroll
            for (int s = 0; s < 4; ++s) {
                aReg[s] = *(const float4*)(aPtr[s] + ko);
                bReg[s] = bValid[s] ? *(const float4*)(bPtr[s] + ko)
                                    : make_float4(0.f, 0.f, 0.f, 0.f);
            }
        }
        short8 af[4], bf[4];
#pragma unroll
        for (int mi = 0; mi < 4; ++mi)
            af[mi] = *(const short8*)&As[(wrow * 64 + mi * 16 + l16) * LDSS + quad * 8];
#pragma unroll
        for (int ni = 0; ni < 4; ++ni)
            bf[ni] = *(const short8*)&Bs[(wcol * 64 + ni * 16 + l16) * LDSS + quad * 8];
#pragma unroll
        for (int mi = 0; mi < 4; ++mi)
#pragma unroll
            for (int ni = 0; ni < 4; ++ni)
                acc[mi][ni] = __builtin_amdgcn_mfma_f32_16x16x32_bf16(
                    af[mi], bf[ni], acc[mi][ni], 0, 0, 0);
        __syncthreads();
    }
#pragma unroll
    for (int mi = 0; mi < 4; ++mi) {
#pragma unroll
        for (int r = 0; r < 4; ++r) {
            float v = FLT_MAX;
#pragma unroll
            for (int ni = 0; ni < 4; ++ni) {
                int gcol = mb + wcol * 64 + ni * 16 + l16;
                float d2 = fmaf(-2.0f, acc[mi][ni][r], 2.0f);
                v = fminf(v, (gcol < MN) ? d2 : FLT_MAX);
            }
            v = fminf(v, __shfl_xor(v, 1));
            v = fminf(v, __shfl_xor(v, 2));
            v = fminf(v, __shfl_xor(v, 4));
            v = fminf(v, __shfl_xor(v, 8));
            if (l16 == 0)
                atomicMin(&qmin[wrow * 64 + mi * 16 + quad * 4 + r], encf(v));
        }
    }
    __syncthreads();
    if (tid < 128) atomicMin(&dminEnc[qb + tid], qmin[tid]);
}

__global__ void finalize(const unsigned* __restrict__ dminEnc, float* __restrict__ out) {
    __shared__ float red[256];
    const int tid = threadIdx.x;
    float mx = 0.f;
    for (int i = tid; i < QN; i += 256) {
        float d2 = decf(dminEnc[i]);
        float d = sqrtf(fmaxf(d2, 0.f));
        out[i] = d;
        mx = fmaxf(mx, d);
    }
    red[tid] = mx;
    __syncthreads();
    for (int s = 128; s > 0; s >>= 1) {
        if (tid < s) red[tid] = fmaxf(red[tid], red[tid + s]);
        __syncthreads();
    }
    if (tid == 0) out[QN] = red[0];
}

extern "C" void kernel_launch(void* const* d_in, const int* in_sizes, int n_in,
                              void* d_out, int out_size, void* d_ws, size_t ws_size,
                              hipStream_t stream)
{
    const float* query  = (const float*)d_in[0];
    const float* memory = (const float*)d_in[1];
    float* out = (float*)d_out;

    const size_t memB_elems = (size_t)MP * DN;          // padded bf16 memory
    const size_t qB_elems   = (size_t)QN * DN;
    const size_t need = memB_elems * 2 + qB_elems * 2 + (size_t)QN * 4;

    if (ws_size >= need) {
        short* mB = (short*)d_ws;
        short* qB = mB + memB_elems;
        unsigned* dminEnc = (unsigned*)(qB + qB_elems);

        hipLaunchKernelGGL(init_min, dim3((QN + 255) / 256), dim3(256), 0, stream, dminEnc);
        {
            long nv = (long)MN * DN, nt = (long)memB_elems;
            int blocks = (int)((nt / 4 + 255) / 256);
            hipLaunchKernelGGL(cvt_bf16, dim3(blocks), dim3(256), 0, stream,
                               memory, mB, nv, nt);
        }
        {
            long nv = (long)qB_elems, nt = (long)qB_elems;
            int blocks = (int)((nt / 4 + 255) / 256);
            hipLaunchKernelGGL(cvt_bf16, dim3(blocks), dim3(256), 0, stream,
                               query, qB, nv, nt);
        }
        hipLaunchKernelGGL(nn_gemm_bf16, dim3(QN / 128, MP / 128), dim3(256), 0, stream,
                           qB, mB, dminEnc);
        hipLaunchKernelGGL(finalize, dim3(1), dim3(256), 0, stream, dminEnc, out);
    } else {
        unsigned* dminEnc = (unsigned*)d_ws;
        hipLaunchKernelGGL(init_min, dim3((QN + 255) / 256), dim3(256), 0, stream, dminEnc);
        hipLaunchKernelGGL(nn_gemm_f32, dim3(QN / 128, (MN + 127) / 128), dim3(256), 0, stream,
                           query, memory, dminEnc);
        hipLaunchKernelGGL(finalize, dim3(1), dim3(256), 0, stream, dminEnc, out);
    }
}